// Round 1
// 648.025 us; speedup vs baseline: 1.5540x; 1.5540x over previous
//
#include <hip/hip_runtime.h>
#include <math.h>

// All tensors fp32. B=256, F=512, H=1024, C=1000.

// ---------------------------------------------------------------------------
// pool_big: wave per row, float4 loads. Segments s1..s4 (rowlen % 4 == 0).
// ---------------------------------------------------------------------------
struct Pool4Segs {
    const float* src[4];
    float*       dst[4];
    int n4[4];        // rowlen / 4
    int cum[4];       // inclusive prefix sum of rows
    float inv[4];
};

__global__ __launch_bounds__(256) void pool_big_kernel(Pool4Segs S, int total_waves) {
    int gid  = blockIdx.x * 256 + threadIdx.x;
    int wave = gid >> 6;
    int lane = gid & 63;
    if (wave >= total_waves) return;
    int s = 0;
    #pragma unroll
    for (int i = 0; i < 3; ++i) if (wave >= S.cum[i]) s = i + 1;
    int row = wave - (s == 0 ? 0 : S.cum[s - 1]);
    const int n4 = S.n4[s];
    const float4* p4 = (const float4*)(S.src[s]) + (size_t)row * n4;
    float acc = 0.f;
    for (int k = lane; k < n4; k += 64) {
        float4 v = p4[k];
        acc += (v.x + v.y) + (v.z + v.w);
    }
    #pragma unroll
    for (int off = 32; off > 0; off >>= 1) acc += __shfl_down(acc, off, 64);
    if (lane == 0) S.dst[s][row] = acc * S.inv[s];
}

// ---------------------------------------------------------------------------
// pool_small: rowlen == 49 (s5 then ff). Block of 256 stages 64 rows into LDS
// coalesced; 4 threads/row reduce (stride-49 LDS = <=2-way conflicts = free).
// ---------------------------------------------------------------------------
__global__ __launch_bounds__(256) void pool_small_kernel(const float* __restrict__ s5,
        const float* __restrict__ ff, float* __restrict__ dst5, float* __restrict__ dstf,
        int rows5) {
    __shared__ float lds[64 * 49];
    const int tid  = threadIdx.x;
    const int row0 = blockIdx.x * 64;
    const float* src;
    float* dst;
    int rbase;
    if (row0 < rows5) { src = s5; dst = dst5; rbase = row0; }
    else              { src = ff; dst = dstf; rbase = row0 - rows5; }
    const float* p = src + (size_t)rbase * 49;
    #pragma unroll
    for (int i = tid; i < 64 * 49; i += 256) lds[i] = p[i];
    __syncthreads();
    const int r  = tid >> 2;
    const int c0 = tid & 3;
    float s = 0.f;
    #pragma unroll
    for (int c = c0; c < 49; c += 4) s += lds[r * 49 + c];
    s += __shfl_down(s, 2, 64);
    s += __shfl_down(s, 1, 64);
    if (c0 == 0) dst[rbase + r] = s * (1.f / 49.f);
}

// ---------------------------------------------------------------------------
// fc_splitk: split-K skinny GEMM partials. Each wave: 256 n-cols (float4 per
// lane) x ROWS m-rows x one K-slice. 1 KB/wave W loads, #pragma unroll 4 for
// ILP; 2048 waves total per layer (8 waves/CU) -> L2-BW-bound, not latency.
// Partials P[ks][M][N]; reduced (deterministically) by reduce_bias_kernel.
// ---------------------------------------------------------------------------
template <int ROWS>
__global__ __launch_bounds__(256) void fc_splitk_kernel(const float* __restrict__ X,
        const float* __restrict__ W, float* __restrict__ P,
        int M, int K, int N, int NW, int Kc, int total_waves) {
    int gid  = blockIdx.x * 256 + threadIdx.x;
    int wave = gid >> 6;
    int lane = gid & 63;
    if (wave >= total_waves) return;
    int wpk = (M / ROWS) * NW;          // waves per K-slice
    int ks  = wave / wpk;
    int rem = wave - ks * wpk;
    int mg  = rem / NW;
    int nw  = rem - mg * NW;
    int n0  = nw * 256 + lane * 4;
    int m0  = mg * ROWS;
    const bool nok = (n0 < N);          // N % 4 == 0 for all layers
    const int  n0s = nok ? n0 : 0;      // keep OOB lanes on a safe address
    int k0 = ks * Kc;
    int k1 = k0 + Kc; if (k1 > K) k1 = K;
    const float* xp = X + (size_t)m0 * K;
    const float* wp = W + n0s;
    float4 acc[ROWS];
    #pragma unroll
    for (int r = 0; r < ROWS; ++r) acc[r] = make_float4(0.f, 0.f, 0.f, 0.f);
    #pragma unroll 4
    for (int k = k0; k < k1; ++k) {
        float4 w = *(const float4*)(wp + (size_t)k * N);
        #pragma unroll
        for (int r = 0; r < ROWS; ++r) {
            float x = xp[(size_t)r * K + k];
            acc[r].x += x * w.x; acc[r].y += x * w.y;
            acc[r].z += x * w.z; acc[r].w += x * w.w;
        }
    }
    if (!nok) return;
    float* pp = P + ((size_t)ks * M + m0) * N + n0;
    #pragma unroll
    for (int r = 0; r < ROWS; ++r) *(float4*)(pp + (size_t)r * N) = acc[r];
}

// Sum KS partial slices + bias (+ReLU). float4 per thread; MN % 4 == 0.
__global__ __launch_bounds__(256) void reduce_bias_kernel(const float* __restrict__ P,
        const float* __restrict__ bias, float* __restrict__ Y,
        int MN, int N, int KS, int do_relu) {
    int i = (blockIdx.x * 256 + threadIdx.x) * 4;
    if (i >= MN) return;
    float4 a = *(const float4*)(P + i);
    for (int s = 1; s < KS; ++s) {
        float4 b = *(const float4*)(P + (size_t)s * MN + i);
        a.x += b.x; a.y += b.y; a.z += b.z; a.w += b.w;
    }
    int n = i - (i / N) * N;            // row length N % 4 == 0 -> no straddle
    float4 bb = *(const float4*)(bias + n);
    a.x += bb.x; a.y += bb.y; a.z += bb.z; a.w += bb.w;
    if (do_relu) {
        a.x = fmaxf(a.x, 0.f); a.y = fmaxf(a.y, 0.f);
        a.z = fmaxf(a.z, 0.f); a.w = fmaxf(a.w, 0.f);
    }
    *(float4*)(Y + i) = a;
}

// ---------------------------------------------------------------------------
// Gate fc3 (K=512 -> 5 logits) fused with top-2 + softmax. One wave per batch.
// jax.lax.top_k tie rule: lower index wins on equality (strict >).
// ---------------------------------------------------------------------------
__global__ __launch_bounds__(64) void fc3_top2_kernel(const float* __restrict__ X,
        const float* __restrict__ W, const float* __restrict__ bias,
        int* __restrict__ topi, float* __restrict__ wsm,
        float* __restrict__ out_gl, float* __restrict__ out_topi,
        float* __restrict__ out_w, int K) {
    const int b = blockIdx.x;
    const int lane = threadIdx.x;
    const float* x = X + (size_t)b * K;
    float acc[5] = {0.f, 0.f, 0.f, 0.f, 0.f};
    for (int k = lane; k < K; k += 64) {
        float xv = x[k];
        const float* wr = W + (size_t)k * 5;
        acc[0] += xv * wr[0]; acc[1] += xv * wr[1]; acc[2] += xv * wr[2];
        acc[3] += xv * wr[3]; acc[4] += xv * wr[4];
    }
    #pragma unroll
    for (int off = 32; off > 0; off >>= 1) {
        #pragma unroll
        for (int j = 0; j < 5; ++j) acc[j] += __shfl_down(acc[j], off, 64);
    }
    if (lane == 0) {
        float v[5];
        #pragma unroll
        for (int j = 0; j < 5; ++j) v[j] = acc[j] + bias[j];
        int i0 = 0;
        #pragma unroll
        for (int i = 1; i < 5; ++i) if (v[i] > v[i0]) i0 = i;
        int i1 = -1;
        #pragma unroll
        for (int i = 0; i < 5; ++i) {
            if (i == i0) continue;
            if (i1 < 0 || v[i] > v[i1]) i1 = i;
        }
        float e1 = __expf(v[i1] - v[i0]);          // v[i0] is the max
        float inv = 1.f / (1.f + e1);
        float w0 = inv, w1 = e1 * inv;
        topi[b * 2] = i0; topi[b * 2 + 1] = i1;
        wsm[b * 2] = w0;  wsm[b * 2 + 1] = w1;
        #pragma unroll
        for (int j = 0; j < 5; ++j) out_gl[b * 5 + j] = v[j];
        out_topi[b * 2]     = (float)i0;
        out_topi[b * 2 + 1] = (float)i1;
        out_w[b * 2]     = w0;
        out_w[b * 2 + 1] = w1;
    }
}

// ---------------------------------------------------------------------------
// Per-batch: the two SELECTED stage projections (Linear + LayerNorm + exact
// GELU), softmax-weighted mixture. One block of 512 per batch element.
// ---------------------------------------------------------------------------
struct ProjParams {
    const float* W[5];
    const float* bp[5];
    const float* g[5];
    const float* be[5];
    int K[5];
    int poff[5];
};

__global__ __launch_bounds__(512) void proj_mix_kernel(ProjParams P,
        const float* __restrict__ pools, const int* __restrict__ topi,
        const float* __restrict__ wsm, float* __restrict__ mix) {
    const int b = blockIdx.x;
    const int f = threadIdx.x;           // 0..511
    __shared__ float sp[160];
    __shared__ float redS[8], redQ[8];
    __shared__ float s_mu, s_rstd;

    float acc = 0.f;
    for (int j = 0; j < 2; ++j) {
        __syncthreads();                 // protect sp / red reuse across iterations
        const int st = topi[b * 2 + j];
        const int K  = P.K[st];
        const float* p = pools + P.poff[st] + (size_t)b * K;
        if (f < K) sp[f] = p[f];
        __syncthreads();

        const float* W = P.W[st];
        float h = P.bp[st][f];
        #pragma unroll 4
        for (int k = 0; k < K; ++k) h += sp[k] * W[(size_t)k * 512 + f];

        // LayerNorm over 512 features (ddof=0)
        float s = h, q = h * h;
        #pragma unroll
        for (int off = 32; off > 0; off >>= 1) {
            s += __shfl_down(s, off, 64);
            q += __shfl_down(q, off, 64);
        }
        const int lane = threadIdx.x & 63, wid = threadIdx.x >> 6;
        if (lane == 0) { redS[wid] = s; redQ[wid] = q; }
        __syncthreads();
        if (threadIdx.x == 0) {
            float ts = 0.f, tq = 0.f;
            #pragma unroll
            for (int i = 0; i < 8; ++i) { ts += redS[i]; tq += redQ[i]; }
            float mu  = ts * (1.f / 512.f);
            float var = tq * (1.f / 512.f) - mu * mu;
            s_mu   = mu;
            s_rstd = rsqrtf(var + 1e-5f);
        }
        __syncthreads();

        float x  = (h - s_mu) * s_rstd * P.g[st][f] + P.be[st][f];
        float ge = 0.5f * x * (1.f + erff(x * 0.70710678118654752f));
        acc += wsm[b * 2 + j] * ge;
    }
    mix[(size_t)b * 512 + f] = acc;
}

// ---------------------------------------------------------------------------
extern "C" void kernel_launch(void* const* d_in, const int* in_sizes, int n_in,
                              void* d_out, int out_size, void* d_ws, size_t ws_size,
                              hipStream_t stream) {
    const int B = 256, F = 512, H = 1024, C = 1000;

    const float* s1 = (const float*)d_in[0];
    const float* s2 = (const float*)d_in[1];
    const float* s3 = (const float*)d_in[2];
    const float* s4 = (const float*)d_in[3];
    const float* s5 = (const float*)d_in[4];
    const float* ff = (const float*)d_in[5];
    const float *Wp[5], *bp[5], *g[5], *be[5];
    for (int i = 0; i < 5; ++i) {
        Wp[i] = (const float*)d_in[6 + 4 * i];
        bp[i] = (const float*)d_in[7 + 4 * i];
        g[i]  = (const float*)d_in[8 + 4 * i];
        be[i] = (const float*)d_in[9 + 4 * i];
    }
    const float* Wg1 = (const float*)d_in[26]; const float* bg1 = (const float*)d_in[27];
    const float* Wg2 = (const float*)d_in[28]; const float* bg2 = (const float*)d_in[29];
    const float* Wg3 = (const float*)d_in[30]; const float* bg3 = (const float*)d_in[31];
    const float* Wc1 = (const float*)d_in[32]; const float* bc1 = (const float*)d_in[33];
    const float* Wc2 = (const float*)d_in[34]; const float* bc2 = (const float*)d_in[35];
    const float* Wc3 = (const float*)d_in[36]; const float* bc3 = (const float*)d_in[37];

    // ---- workspace layout (fp32 elements) ----
    float* ws = (float*)d_ws;
    const int Ks[5]   = {16, 24, 40, 80, 160};
    const int poff[5] = {0, 4096, 10240, 20480, 40960};      // B*K prefix sums
    float* pools    = ws;                                     // 81920
    float* gate_in  = ws + 81920;                             // 245760
    float* g1h      = ws + 327680;                            // 262144
    float* g2h      = ws + 589824;                            // 131072
    float* wsm      = ws + 722176;                            // 512
    int*   topi     = (int*)(ws + 722688);                    // 512
    float* mix      = ws + 723200;                            // 131072
    float* c1h      = ws + 854272;                            // 262144
    float* c2h      = ws + 1116416;                           // 131072
    float* partials = ws + 1247488;                           // 1048576 (4 MB slab)

    float* out      = (float*)d_out;
    float* out_gl   = out + 256000;
    float* out_topi = out + 257280;
    float* out_w    = out + 257792;

    // ---- 1a) pooling: big rows (s1..s4), wave per row ----
    Pool4Segs S;
    {
        const float* srcs[4] = { s1, s2, s3, s4 };
        float* dsts[4] = { pools + poff[0], pools + poff[1], pools + poff[2], pools + poff[3] };
        const int rls[4]  = { 112 * 112, 56 * 56, 28 * 28, 14 * 14 };
        const int rows[4] = { B * 16, B * 24, B * 40, B * 80 };
        int cum = 0;
        for (int i = 0; i < 4; ++i) {
            S.src[i] = srcs[i]; S.dst[i] = dsts[i]; S.n4[i] = rls[i] / 4;
            cum += rows[i]; S.cum[i] = cum; S.inv[i] = 1.f / rls[i];
        }
        int blocks = (cum * 64 + 255) / 256;   // cum = 40960 waves
        pool_big_kernel<<<blocks, 256, 0, stream>>>(S, cum);
    }
    // ---- 1b) pooling: rowlen-49 (s5, ff) via LDS staging, 64 rows/block ----
    {
        int rows5 = B * 160;                  // 40960, divisible by 64
        int total = rows5 + B * 960;          // 286720
        pool_small_kernel<<<total / 64, 256, 0, stream>>>(s5, ff, pools + poff[4], gate_in, rows5);
    }

    // split-K FC: partials then deterministic reduce (+bias, +relu)
    auto fc = [&](const float* X, const float* W, const float* bias, float* Y,
                  int M, int K, int N, int KS, int do_relu) {
        int NW = (N + 255) / 256;
        int Kc = (K + KS - 1) / KS;
        int waves  = KS * (M / 2) * NW;       // 2048 for all five layers
        int blocks = (waves * 64 + 255) / 256;
        fc_splitk_kernel<2><<<blocks, 256, 0, stream>>>(X, W, partials, M, K, N, NW, Kc, waves);
        int MN = M * N;
        reduce_bias_kernel<<<(MN / 4 + 255) / 256, 256, 0, stream>>>(
            partials, bias, Y, MN, N, KS, do_relu);
    };

    // ---- 2) gate MLP ----
    fc(gate_in, Wg1, bg1, g1h, B, 960, H, 4, 1);
    fc(g1h, Wg2, bg2, g2h, B, H, H / 2, 8, 1);
    fc3_top2_kernel<<<B, 64, 0, stream>>>(g2h, Wg3, bg3, topi, wsm,
                                          out_gl, out_topi, out_w, H / 2);

    // ---- 3) selected projections + mixture ----
    ProjParams P;
    for (int i = 0; i < 5; ++i) {
        P.W[i] = Wp[i]; P.bp[i] = bp[i]; P.g[i] = g[i]; P.be[i] = be[i];
        P.K[i] = Ks[i]; P.poff[i] = poff[i];
    }
    proj_mix_kernel<<<B, 512, 0, stream>>>(P, pools, topi, wsm, mix);

    // ---- 4) classifier MLP ----
    fc(mix, Wc1, bc1, c1h, B, F, H, 4, 1);
    fc(c1h, Wc2, bc2, c2h, B, H, H / 2, 8, 1);
    fc(c2h, Wc3, bc3, out, B, H / 2, C, 4, 0);
}

// Round 2
// 634.832 us; speedup vs baseline: 1.5863x; 1.0208x over previous
//
#include <hip/hip_runtime.h>
#include <math.h>

// All tensors fp32. B=256, F=512, H=1024, C=1000.

// ---------------------------------------------------------------------------
// pool_big: wave per row, float4 loads, 8-deep MLP unroll (independent
// accumulators keep 8 loads in flight per lane -> latency-bound fix).
// Segments s1..s4 (rowlen % 4 == 0).
// ---------------------------------------------------------------------------
struct Pool4Segs {
    const float* src[4];
    float*       dst[4];
    int n4[4];        // rowlen / 4
    int cum[4];       // inclusive prefix sum of rows
    float inv[4];
};

__global__ __launch_bounds__(256) void pool_big_kernel(Pool4Segs S, int total_waves) {
    int gid  = blockIdx.x * 256 + threadIdx.x;
    int wave = gid >> 6;
    int lane = gid & 63;
    if (wave >= total_waves) return;
    int s = 0;
    #pragma unroll
    for (int i = 0; i < 3; ++i) if (wave >= S.cum[i]) s = i + 1;
    int row = wave - (s == 0 ? 0 : S.cum[s - 1]);
    const int n4 = S.n4[s];
    const float4* p4 = (const float4*)(S.src[s]) + (size_t)row * n4;

    float a0 = 0.f, a1 = 0.f, a2 = 0.f, a3 = 0.f;
    float a4 = 0.f, a5 = 0.f, a6 = 0.f, a7 = 0.f;
    int k = lane;
    // 8-deep: 8 independent float4 loads in flight (s1: 6 full groups)
    for (; k + 448 < n4; k += 512) {
        float4 v0 = p4[k];       float4 v1 = p4[k + 64];
        float4 v2 = p4[k + 128]; float4 v3 = p4[k + 192];
        float4 v4 = p4[k + 256]; float4 v5 = p4[k + 320];
        float4 v6 = p4[k + 384]; float4 v7 = p4[k + 448];
        a0 += (v0.x + v0.y) + (v0.z + v0.w);
        a1 += (v1.x + v1.y) + (v1.z + v1.w);
        a2 += (v2.x + v2.y) + (v2.z + v2.w);
        a3 += (v3.x + v3.y) + (v3.z + v3.w);
        a4 += (v4.x + v4.y) + (v4.z + v4.w);
        a5 += (v5.x + v5.y) + (v5.z + v5.w);
        a6 += (v6.x + v6.y) + (v6.z + v6.w);
        a7 += (v7.x + v7.y) + (v7.z + v7.w);
    }
    // 4-deep tail (s2 mid, s3 head)
    for (; k + 192 < n4; k += 256) {
        float4 v0 = p4[k];       float4 v1 = p4[k + 64];
        float4 v2 = p4[k + 128]; float4 v3 = p4[k + 192];
        a0 += (v0.x + v0.y) + (v0.z + v0.w);
        a1 += (v1.x + v1.y) + (v1.z + v1.w);
        a2 += (v2.x + v2.y) + (v2.z + v2.w);
        a3 += (v3.x + v3.y) + (v3.z + v3.w);
    }
    // scalar tail
    for (; k < n4; k += 64) {
        float4 v = p4[k];
        a0 += (v.x + v.y) + (v.z + v.w);
    }
    float acc = ((a0 + a1) + (a2 + a3)) + ((a4 + a5) + (a6 + a7));
    #pragma unroll
    for (int off = 32; off > 0; off >>= 1) acc += __shfl_down(acc, off, 64);
    if (lane == 0) S.dst[s][row] = acc * S.inv[s];
}

// ---------------------------------------------------------------------------
// pool_small: rowlen == 49 (s5 then ff). Block of 256 stages 64 rows into LDS
// via fully-unrolled float4 loads (64*49 floats = 784 float4, 16B aligned
// since rbase%64==0 -> 64*49*4 = 784*16 bytes/block). 4 threads/row reduce.
// ---------------------------------------------------------------------------
__global__ __launch_bounds__(256) void pool_small_kernel(const float* __restrict__ s5,
        const float* __restrict__ ff, float* __restrict__ dst5, float* __restrict__ dstf,
        int rows5) {
    __shared__ float lds[64 * 49];
    const int tid  = threadIdx.x;
    const int row0 = blockIdx.x * 64;
    const float* src;
    float* dst;
    int rbase;
    if (row0 < rows5) { src = s5; dst = dst5; rbase = row0; }
    else              { src = ff; dst = dstf; rbase = row0 - rows5; }
    const float4* p4 = (const float4*)(src + (size_t)rbase * 49);
    float4* l4 = (float4*)lds;
    // 784 float4 total: 3 full rounds of 256 + 16-thread tail, all independent
    float4 v0 = p4[tid];
    float4 v1 = p4[tid + 256];
    float4 v2 = p4[tid + 512];
    float4 v3;
    const bool t3 = (tid < 784 - 768);
    if (t3) v3 = p4[tid + 768];
    l4[tid]       = v0;
    l4[tid + 256] = v1;
    l4[tid + 512] = v2;
    if (t3) l4[tid + 768] = v3;
    __syncthreads();
    const int r  = tid >> 2;
    const int c0 = tid & 3;
    float s = 0.f;
    #pragma unroll
    for (int c = c0; c < 49; c += 4) s += lds[r * 49 + c];
    s += __shfl_down(s, 2, 64);
    s += __shfl_down(s, 1, 64);
    if (c0 == 0) dst[rbase + r] = s * (1.f / 49.f);
}

// ---------------------------------------------------------------------------
// fc_splitk: split-K skinny GEMM partials. Each wave: 256 n-cols (float4 per
// lane) x ROWS m-rows x one K-slice. 1 KB/wave W loads, #pragma unroll 4 for
// ILP; 2048 waves total per layer (8 waves/CU) -> L2-BW-bound, not latency.
// Partials P[ks][M][N]; reduced (deterministically) by reduce_bias_kernel.
// ---------------------------------------------------------------------------
template <int ROWS>
__global__ __launch_bounds__(256) void fc_splitk_kernel(const float* __restrict__ X,
        const float* __restrict__ W, float* __restrict__ P,
        int M, int K, int N, int NW, int Kc, int total_waves) {
    int gid  = blockIdx.x * 256 + threadIdx.x;
    int wave = gid >> 6;
    int lane = gid & 63;
    if (wave >= total_waves) return;
    int wpk = (M / ROWS) * NW;          // waves per K-slice
    int ks  = wave / wpk;
    int rem = wave - ks * wpk;
    int mg  = rem / NW;
    int nw  = rem - mg * NW;
    int n0  = nw * 256 + lane * 4;
    int m0  = mg * ROWS;
    const bool nok = (n0 < N);          // N % 4 == 0 for all layers
    const int  n0s = nok ? n0 : 0;      // keep OOB lanes on a safe address
    int k0 = ks * Kc;
    int k1 = k0 + Kc; if (k1 > K) k1 = K;
    const float* xp = X + (size_t)m0 * K;
    const float* wp = W + n0s;
    float4 acc[ROWS];
    #pragma unroll
    for (int r = 0; r < ROWS; ++r) acc[r] = make_float4(0.f, 0.f, 0.f, 0.f);
    #pragma unroll 4
    for (int k = k0; k < k1; ++k) {
        float4 w = *(const float4*)(wp + (size_t)k * N);
        #pragma unroll
        for (int r = 0; r < ROWS; ++r) {
            float x = xp[(size_t)r * K + k];
            acc[r].x += x * w.x; acc[r].y += x * w.y;
            acc[r].z += x * w.z; acc[r].w += x * w.w;
        }
    }
    if (!nok) return;
    float* pp = P + ((size_t)ks * M + m0) * N + n0;
    #pragma unroll
    for (int r = 0; r < ROWS; ++r) *(float4*)(pp + (size_t)r * N) = acc[r];
}

// Sum KS partial slices + bias (+ReLU). float4 per thread; MN % 4 == 0.
__global__ __launch_bounds__(256) void reduce_bias_kernel(const float* __restrict__ P,
        const float* __restrict__ bias, float* __restrict__ Y,
        int MN, int N, int KS, int do_relu) {
    int i = (blockIdx.x * 256 + threadIdx.x) * 4;
    if (i >= MN) return;
    float4 a = *(const float4*)(P + i);
    for (int s = 1; s < KS; ++s) {
        float4 b = *(const float4*)(P + (size_t)s * MN + i);
        a.x += b.x; a.y += b.y; a.z += b.z; a.w += b.w;
    }
    int n = i - (i / N) * N;            // row length N % 4 == 0 -> no straddle
    float4 bb = *(const float4*)(bias + n);
    a.x += bb.x; a.y += bb.y; a.z += bb.z; a.w += bb.w;
    if (do_relu) {
        a.x = fmaxf(a.x, 0.f); a.y = fmaxf(a.y, 0.f);
        a.z = fmaxf(a.z, 0.f); a.w = fmaxf(a.w, 0.f);
    }
    *(float4*)(Y + i) = a;
}

// ---------------------------------------------------------------------------
// Gate fc3 (K=512 -> 5 logits) fused with top-2 + softmax. One wave per batch.
// jax.lax.top_k tie rule: lower index wins on equality (strict >).
// ---------------------------------------------------------------------------
__global__ __launch_bounds__(64) void fc3_top2_kernel(const float* __restrict__ X,
        const float* __restrict__ W, const float* __restrict__ bias,
        int* __restrict__ topi, float* __restrict__ wsm,
        float* __restrict__ out_gl, float* __restrict__ out_topi,
        float* __restrict__ out_w, int K) {
    const int b = blockIdx.x;
    const int lane = threadIdx.x;
    const float* x = X + (size_t)b * K;
    float acc[5] = {0.f, 0.f, 0.f, 0.f, 0.f};
    for (int k = lane; k < K; k += 64) {
        float xv = x[k];
        const float* wr = W + (size_t)k * 5;
        acc[0] += xv * wr[0]; acc[1] += xv * wr[1]; acc[2] += xv * wr[2];
        acc[3] += xv * wr[3]; acc[4] += xv * wr[4];
    }
    #pragma unroll
    for (int off = 32; off > 0; off >>= 1) {
        #pragma unroll
        for (int j = 0; j < 5; ++j) acc[j] += __shfl_down(acc[j], off, 64);
    }
    if (lane == 0) {
        float v[5];
        #pragma unroll
        for (int j = 0; j < 5; ++j) v[j] = acc[j] + bias[j];
        int i0 = 0;
        #pragma unroll
        for (int i = 1; i < 5; ++i) if (v[i] > v[i0]) i0 = i;
        int i1 = -1;
        #pragma unroll
        for (int i = 0; i < 5; ++i) {
            if (i == i0) continue;
            if (i1 < 0 || v[i] > v[i1]) i1 = i;
        }
        float e1 = __expf(v[i1] - v[i0]);          // v[i0] is the max
        float inv = 1.f / (1.f + e1);
        float w0 = inv, w1 = e1 * inv;
        topi[b * 2] = i0; topi[b * 2 + 1] = i1;
        wsm[b * 2] = w0;  wsm[b * 2 + 1] = w1;
        #pragma unroll
        for (int j = 0; j < 5; ++j) out_gl[b * 5 + j] = v[j];
        out_topi[b * 2]     = (float)i0;
        out_topi[b * 2 + 1] = (float)i1;
        out_w[b * 2]     = w0;
        out_w[b * 2 + 1] = w1;
    }
}

// ---------------------------------------------------------------------------
// Per-batch: the two SELECTED stage projections (Linear + LayerNorm + exact
// GELU), softmax-weighted mixture. One block of 512 per batch element.
// ---------------------------------------------------------------------------
struct ProjParams {
    const float* W[5];
    const float* bp[5];
    const float* g[5];
    const float* be[5];
    int K[5];
    int poff[5];
};

__global__ __launch_bounds__(512) void proj_mix_kernel(ProjParams P,
        const float* __restrict__ pools, const int* __restrict__ topi,
        const float* __restrict__ wsm, float* __restrict__ mix) {
    const int b = blockIdx.x;
    const int f = threadIdx.x;           // 0..511
    __shared__ float sp[160];
    __shared__ float redS[8], redQ[8];
    __shared__ float s_mu, s_rstd;

    float acc = 0.f;
    for (int j = 0; j < 2; ++j) {
        __syncthreads();                 // protect sp / red reuse across iterations
        const int st = topi[b * 2 + j];
        const int K  = P.K[st];
        const float* p = pools + P.poff[st] + (size_t)b * K;
        if (f < K) sp[f] = p[f];
        __syncthreads();

        const float* W = P.W[st];
        float h = P.bp[st][f];
        #pragma unroll 4
        for (int k = 0; k < K; ++k) h += sp[k] * W[(size_t)k * 512 + f];

        // LayerNorm over 512 features (ddof=0)
        float s = h, q = h * h;
        #pragma unroll
        for (int off = 32; off > 0; off >>= 1) {
            s += __shfl_down(s, off, 64);
            q += __shfl_down(q, off, 64);
        }
        const int lane = threadIdx.x & 63, wid = threadIdx.x >> 6;
        if (lane == 0) { redS[wid] = s; redQ[wid] = q; }
        __syncthreads();
        if (threadIdx.x == 0) {
            float ts = 0.f, tq = 0.f;
            #pragma unroll
            for (int i = 0; i < 8; ++i) { ts += redS[i]; tq += redQ[i]; }
            float mu  = ts * (1.f / 512.f);
            float var = tq * (1.f / 512.f) - mu * mu;
            s_mu   = mu;
            s_rstd = rsqrtf(var + 1e-5f);
        }
        __syncthreads();

        float x  = (h - s_mu) * s_rstd * P.g[st][f] + P.be[st][f];
        float ge = 0.5f * x * (1.f + erff(x * 0.70710678118654752f));
        acc += wsm[b * 2 + j] * ge;
    }
    mix[(size_t)b * 512 + f] = acc;
}

// ---------------------------------------------------------------------------
extern "C" void kernel_launch(void* const* d_in, const int* in_sizes, int n_in,
                              void* d_out, int out_size, void* d_ws, size_t ws_size,
                              hipStream_t stream) {
    const int B = 256, F = 512, H = 1024, C = 1000;

    const float* s1 = (const float*)d_in[0];
    const float* s2 = (const float*)d_in[1];
    const float* s3 = (const float*)d_in[2];
    const float* s4 = (const float*)d_in[3];
    const float* s5 = (const float*)d_in[4];
    const float* ff = (const float*)d_in[5];
    const float *Wp[5], *bp[5], *g[5], *be[5];
    for (int i = 0; i < 5; ++i) {
        Wp[i] = (const float*)d_in[6 + 4 * i];
        bp[i] = (const float*)d_in[7 + 4 * i];
        g[i]  = (const float*)d_in[8 + 4 * i];
        be[i] = (const float*)d_in[9 + 4 * i];
    }
    const float* Wg1 = (const float*)d_in[26]; const float* bg1 = (const float*)d_in[27];
    const float* Wg2 = (const float*)d_in[28]; const float* bg2 = (const float*)d_in[29];
    const float* Wg3 = (const float*)d_in[30]; const float* bg3 = (const float*)d_in[31];
    const float* Wc1 = (const float*)d_in[32]; const float* bc1 = (const float*)d_in[33];
    const float* Wc2 = (const float*)d_in[34]; const float* bc2 = (const float*)d_in[35];
    const float* Wc3 = (const float*)d_in[36]; const float* bc3 = (const float*)d_in[37];

    // ---- workspace layout (fp32 elements) ----
    float* ws = (float*)d_ws;
    const int Ks[5]   = {16, 24, 40, 80, 160};
    const int poff[5] = {0, 4096, 10240, 20480, 40960};      // B*K prefix sums
    float* pools    = ws;                                     // 81920
    float* gate_in  = ws + 81920;                             // 245760
    float* g1h      = ws + 327680;                            // 262144
    float* g2h      = ws + 589824;                             // 131072
    float* wsm      = ws + 722176;                            // 512
    int*   topi     = (int*)(ws + 722688);                    // 512
    float* mix      = ws + 723200;                            // 131072
    float* c1h      = ws + 854272;                            // 262144
    float* c2h      = ws + 1116416;                           // 131072
    float* partials = ws + 1247488;                           // 1048576 (4 MB slab)

    float* out      = (float*)d_out;
    float* out_gl   = out + 256000;
    float* out_topi = out + 257280;
    float* out_w    = out + 257792;

    // ---- 1a) pooling: big rows (s1..s4), wave per row ----
    Pool4Segs S;
    {
        const float* srcs[4] = { s1, s2, s3, s4 };
        float* dsts[4] = { pools + poff[0], pools + poff[1], pools + poff[2], pools + poff[3] };
        const int rls[4]  = { 112 * 112, 56 * 56, 28 * 28, 14 * 14 };
        const int rows[4] = { B * 16, B * 24, B * 40, B * 80 };
        int cum = 0;
        for (int i = 0; i < 4; ++i) {
            S.src[i] = srcs[i]; S.dst[i] = dsts[i]; S.n4[i] = rls[i] / 4;
            cum += rows[i]; S.cum[i] = cum; S.inv[i] = 1.f / rls[i];
        }
        int blocks = (cum * 64 + 255) / 256;   // cum = 40960 waves
        pool_big_kernel<<<blocks, 256, 0, stream>>>(S, cum);
    }
    // ---- 1b) pooling: rowlen-49 (s5, ff) via LDS staging, 64 rows/block ----
    {
        int rows5 = B * 160;                  // 40960, divisible by 64
        int total = rows5 + B * 960;          // 286720
        pool_small_kernel<<<total / 64, 256, 0, stream>>>(s5, ff, pools + poff[4], gate_in, rows5);
    }

    // split-K FC: partials then deterministic reduce (+bias, +relu)
    auto fc = [&](const float* X, const float* W, const float* bias, float* Y,
                  int M, int K, int N, int KS, int do_relu) {
        int NW = (N + 255) / 256;
        int Kc = (K + KS - 1) / KS;
        int waves  = KS * (M / 2) * NW;       // 2048 for all five layers
        int blocks = (waves * 64 + 255) / 256;
        fc_splitk_kernel<2><<<blocks, 256, 0, stream>>>(X, W, partials, M, K, N, NW, Kc, waves);
        int MN = M * N;
        reduce_bias_kernel<<<(MN / 4 + 255) / 256, 256, 0, stream>>>(
            partials, bias, Y, MN, N, KS, do_relu);
    };

    // ---- 2) gate MLP ----
    fc(gate_in, Wg1, bg1, g1h, B, 960, H, 4, 1);
    fc(g1h, Wg2, bg2, g2h, B, H, H / 2, 8, 1);
    fc3_top2_kernel<<<B, 64, 0, stream>>>(g2h, Wg3, bg3, topi, wsm,
                                          out_gl, out_topi, out_w, H / 2);

    // ---- 3) selected projections + mixture ----
    ProjParams P;
    for (int i = 0; i < 5; ++i) {
        P.W[i] = Wp[i]; P.bp[i] = bp[i]; P.g[i] = g[i]; P.be[i] = be[i];
        P.K[i] = Ks[i]; P.poff[i] = poff[i];
    }
    proj_mix_kernel<<<B, 512, 0, stream>>>(P, pools, topi, wsm, mix);

    // ---- 4) classifier MLP ----
    fc(mix, Wc1, bc1, c1h, B, F, H, 4, 1);
    fc(c1h, Wc2, bc2, c2h, B, H, H / 2, 8, 1);
    fc(c2h, Wc3, bc3, out, B, H / 2, C, 4, 0);
}